// Round 15
// baseline (467.408 us; speedup 1.0000x reference)
//
#include <hip/hip_runtime.h>

#define OFF_H 1048576
#define OFF_A 34603008
#define KROW 84     // dwords per m-row of K tile (4h x 20 + 4 pad)
#define KHS  20     // dwords per head within K row
#define VROW 36     // dwords per (h,d) row of V tile (32 m-dwords + 4 pad)
#define ATROW 20    // dwords per l-row of At tile
#define AT_OFF 9216 // At region after V region (dwords)

typedef __fp16 h2v __attribute__((ext_vector_type(2)));
typedef _Float16 f16x8 __attribute__((ext_vector_type(8)));
typedef float f32x4 __attribute__((ext_vector_type(4)));

__device__ __forceinline__ void stage_k(unsigned* smem, const float* QKV, size_t qb,
                                        int M, int s, int sm, int dq, int hl){
  float4 ld[8];
  const float* src = QKV + qb + (size_t)(M + sm)*768 + 256 + hl*4;
  #pragma unroll
  for (int i = 0; i < 8; i++) ld[i] = *(const float4*)(src + (dq*8 + i)*8);
  #pragma unroll
  for (int j = 0; j < 4; j++){
    #pragma unroll
    for (int p = 0; p < 4; p++){
      h2v pk = __builtin_amdgcn_cvt_pkrtz(((const float*)&ld[2*p])[j], ((const float*)&ld[2*p+1])[j]);
      *(h2v*)&smem[(s*64 + sm)*KROW + j*KHS + dq*4 + p] = pk;
    }
  }
}

__device__ __forceinline__ void stage_v(unsigned* smem, const float* QKV, size_t qb,
                                        int M, int s, int sm, int dq, int hl){
  float4 ld[8];
  const float* src = QKV + qb + (size_t)(M + sm)*768 + 512 + hl*4;
  #pragma unroll
  for (int i = 0; i < 8; i++) ld[i] = *(const float4*)(src + (dq*8 + i)*8);
  __fp16* hp = (__fp16*)smem;
  #pragma unroll
  for (int j = 0; j < 4; j++){
    #pragma unroll
    for (int i = 0; i < 8; i++){
      hp[((s*128 + j*32 + dq*8 + i)*VROW)*2 + sm] = (__fp16)(((const float*)&ld[i])[j]);
    }
  }
}

__global__ __launch_bounds__(256, 4) void egt_mfma(
    const float* __restrict__ QKV, const float* __restrict__ E,
    const float* __restrict__ G, float* __restrict__ out)
{
  __shared__ __align__(16) unsigned smem[10752];  // 43 KB: K(2x64xKROW) / V(2x128xVROW)+At

  const int t    = threadIdx.x;
  const int lane = t & 63;
  const int wv   = t >> 6;         // 0..3 -> h local
  const int g    = lane >> 4;      // 0..3
  const int c    = lane & 15;      // 0..15
  const int blk  = blockIdx.x;
  const int b    = blk >> 7;
  const int lt   = (blk >> 1) & 63;
  const int hl   = blk & 1;
  const int h    = hl*4 + wv;
  const int l0   = lt << 4;
  const size_t qb = (size_t)b * 786432;
  const int sm = t >> 2;           // staging m-row 0..63
  const int dq = t & 3;            // staging d-quad

  // ---- Q A-fragment: slot(lane,j) = Q[l0+c][d=8g+j] for head h ----
  f16x8 qf;
  {
    const float* qp = QKV + qb + (size_t)(l0 + c)*768 + g*64 + h;
    #pragma unroll
    for (int p = 0; p < 4; p++)
      ((h2v*)&qf)[p] = __builtin_amdgcn_cvt_pkrtz(qp[p*16], qp[p*16+8]);
  }

  // ================= PHASE 1: H_hat + expsum =================
  float esum[4] = {0.f, 0.f, 0.f, 0.f};
  stage_k(smem, QKV, qb, 0, 0, sm, dq, hl);
  __syncthreads();

  for (int pp = 0; pp < 16; pp++){
    const int s = pp & 1;
    if (pp < 15) stage_k(smem, QKV, qb, (pp+1)*64, s^1, sm, dq, hl);
    const int Mb = pp*64;
    #pragma unroll
    for (int q2 = 0; q2 < 4; q2++){       // four 16-m subtiles per period
      const int mrow = q2*16 + c;
      f16x8 kf = *(const f16x8*)&smem[(s*64 + mrow)*KROW + wv*KHS + g*4];
      f32x4 z = {0.f, 0.f, 0.f, 0.f};
      f32x4 sc = __builtin_amdgcn_mfma_f32_16x16x32_f16(qf, kf, z, 0, 0, 0);
      const int mg = Mb + q2*16 + c;
      #pragma unroll
      for (int r = 0; r < 4; r++){
        const int idx = ((b*1024 + l0 + 4*g + r)*1024 + mg)*8 + h;
        float hv = fminf(fmaxf(sc[r], -5.f), 5.f) + E[idx];
        out[OFF_H + idx] = hv;
        esum[r] += __expf(hv);
      }
    }
    __syncthreads();
  }

  // reduce expsum over the 16 m-lanes (c bits), convert to reciprocal
  #pragma unroll
  for (int r = 0; r < 4; r++){
    float v = esum[r];
    v += __shfl_xor(v, 1); v += __shfl_xor(v, 2);
    v += __shfl_xor(v, 4); v += __shfl_xor(v, 8);
    esum[r] = 1.f / v;
  }

  // ================= PHASE 2: A_tild + degrees + PV =================
  float dsum[4] = {0.f, 0.f, 0.f, 0.f};
  f32x4 vc0 = {0.f, 0.f, 0.f, 0.f}, vc1 = {0.f, 0.f, 0.f, 0.f};
  __fp16* hp = (__fp16*)smem;
  const int atbase = AT_OFF + wv*16*ATROW;

  stage_v(smem, QKV, qb, 0, 0, sm, dq, hl);
  __syncthreads();

  for (int pp = 0; pp < 16; pp++){
    const int s = pp & 1;
    if (pp < 15) stage_v(smem, QKV, qb, (pp+1)*64, s^1, sm, dq, hl);
    #pragma unroll
    for (int u2 = 0; u2 < 2; u2++){       // two 32-m chunks per period
      const int Mc = pp*64 + u2*32;
      // compute A_tild in C-pattern, write to per-wave At tile (LDS)
      #pragma unroll
      for (int u = 0; u < 2; u++){
        #pragma unroll
        for (int r = 0; r < 4; r++){
          const int m = Mc + u*16 + c;
          const int idx = ((b*1024 + l0 + 4*g + r)*1024 + m)*8 + h;
          float ha = out[OFF_H + idx];
          float ga = G[idx];
          float sig = 1.f / (1.f + __expf(-ga));
          float A = __expf(ha) * esum[r] * sig;
          dsum[r] += sig;
          out[OFF_A + idx] = A;
          hp[(atbase + (4*g + r)*ATROW)*2 + (u*16 + c)] = (__fp16)A;
        }
      }
      // A-frag + V-frags, two PV mfmas (d-halves)
      f16x8 af  = *(const f16x8*)&smem[atbase + c*ATROW + 4*g];
      f16x8 vf0 = *(const f16x8*)&smem[(s*128 + wv*32 + c)*VROW      + u2*16 + 4*g];
      f16x8 vf1 = *(const f16x8*)&smem[(s*128 + wv*32 + 16 + c)*VROW + u2*16 + 4*g];
      vc0 = __builtin_amdgcn_mfma_f32_16x16x32_f16(af, vf0, vc0, 0, 0, 0);
      vc1 = __builtin_amdgcn_mfma_f32_16x16x32_f16(af, vf1, vc1, 0, 0, 0);
    }
    __syncthreads();
  }

  // degrees -> log1p scalers (reduce over c-lanes), scale + store V_att
  #pragma unroll
  for (int r = 0; r < 4; r++){
    float v = dsum[r];
    v += __shfl_xor(v, 1); v += __shfl_xor(v, 2);
    v += __shfl_xor(v, 4); v += __shfl_xor(v, 8);
    float sc = log1pf(v);
    const int obase = (b*1024 + l0 + 4*g + r)*256 + h;
    out[obase + c*8]      = vc0[r] * sc;
    out[obase + (c+16)*8] = vc1[r] * sc;
  }
}

extern "C" void kernel_launch(void* const* d_in, const int* in_sizes, int n_in,
                              void* d_out, int out_size, void* d_ws, size_t ws_size,
                              hipStream_t stream) {
  const float* QKV = (const float*)d_in[0];
  const float* E   = (const float*)d_in[1];
  const float* G   = (const float*)d_in[2];
  float* out = (float*)d_out;
  egt_mfma<<<dim3(512), 256, 0, stream>>>(QKV, E, G, out);
}

// Round 16
// 169.877 us; speedup vs baseline: 2.7515x; 2.7515x over previous
//
#include <hip/hip_runtime.h>

#define OFF_H 1048576
#define OFF_A 34603008
// Light barrier: orders LDS ops only; leaves global loads in flight.
#define LBAR() asm volatile("s_waitcnt lgkmcnt(0)\n\ts_barrier" ::: "memory")

typedef __fp16 h2v __attribute__((ext_vector_type(2)));
typedef _Float16 f16x8 __attribute__((ext_vector_type(8)));
typedef float f32x4 __attribute__((ext_vector_type(4)));

__global__ __launch_bounds__(512, 2) void egt_mfma2(
    const float* __restrict__ QKV, const float* __restrict__ E,
    const float* __restrict__ G, float* __restrict__ out)
{
  __shared__ __align__(16) h2v   klds[5248];   // K: [m32][h8][dp16] stride 164 dw
  __shared__ __align__(16) float sct[4224];    // scores: [h8][l16][m32] stride 33
  __shared__ __align__(16) __fp16 vl16[10240]; // V^T: [h8][d32][m32] stride 40
  __shared__ __align__(16) __fp16 al16[5120];  // A: [h8][l16][m32] stride 40
  __shared__ float fin[16*9];

  const int t    = threadIdx.x;
  const int lane = t & 63;
  const int wv   = t >> 6;          // mfma domain: head
  const int g    = lane >> 4, c = lane & 15;
  const int cl   = t >> 5,  cu = t & 31;   // coalesced domain: (l, m-chunk)
  const int sm   = t >> 4,  sch = t & 15;  // staging: (m-row, 16-float chunk)
  const int b    = blockIdx.x >> 6;
  const int l0   = (blockIdx.x & 63) << 4;
  const size_t qb = (size_t)b * 786432;
  const size_t erow = (size_t)(b*1024 + l0 + cl) * 8192 + cu*8;

  // ---- Q fragment: qf[j] = Q[l0+c][d=8g+j], head wv ----
  f16x8 qf;
  {
    const float* qp = QKV + qb + (size_t)(l0 + c)*768 + g*64 + wv;
    #pragma unroll
    for (int p2 = 0; p2 < 4; p2++)
      ((h2v*)&qf)[p2] = __builtin_amdgcn_cvt_pkrtz(qp[p2*16], qp[p2*16+8]);
  }

  float esum[8] = {0.f,0.f,0.f,0.f,0.f,0.f,0.f,0.f};
  float4 e4[2][2], k4[4];

  // ---- phase-1 prologue: K(0)->klds, K(1)+E(0),E(1) in flight ----
  {
    const float* ks = QKV + qb + (size_t)sm*768 + 256 + sch*16;
    #pragma unroll
    for (int i = 0; i < 4; i++) k4[i] = *(const float4*)(ks + i*4);
    e4[0][0] = *(const float4*)&E[erow];
    e4[0][1] = *(const float4*)&E[erow + 4];
    e4[1][0] = *(const float4*)&E[erow + 256];
    e4[1][1] = *(const float4*)&E[erow + 260];
    const float* kf_ = (const float*)k4;
    #pragma unroll
    for (int j = 0; j < 8; j++)
      klds[sm*164 + j*20 + sch] = __builtin_amdgcn_cvt_pkrtz(kf_[j], kf_[j+8]);
    const float* ks1 = QKV + qb + (size_t)(32 + sm)*768 + 256 + sch*16;
    #pragma unroll
    for (int i = 0; i < 4; i++) k4[i] = *(const float4*)(ks1 + i*4);
  }
  __syncthreads();

  // ================= PHASE 1 =================
  #pragma unroll 2
  for (int p = 0; p < 32; p++){
    // A: QK mfma -> sct (C layout: row l=4g+r, col m=c)
    #pragma unroll
    for (int sub = 0; sub < 2; sub++){
      f16x8 kf = *(const f16x8*)&klds[(sub*16 + c)*164 + wv*20 + 4*g];
      f32x4 z = {0.f,0.f,0.f,0.f};
      f32x4 s = __builtin_amdgcn_mfma_f32_16x16x32_f16(qf, kf, z, 0, 0, 0);
      #pragma unroll
      for (int r = 0; r < 4; r++)
        sct[wv*528 + (4*g+r)*33 + sub*16 + c] = s[r];
    }
    LBAR();
    // B: stage K(p+1)->klds, issue K(p+2); coalesced elementwise
    if (p+1 < 32){
      const float* kf_ = (const float*)k4;
      #pragma unroll
      for (int j = 0; j < 8; j++)
        klds[sm*164 + j*20 + sch] = __builtin_amdgcn_cvt_pkrtz(kf_[j], kf_[j+8]);
    }
    if (p+2 < 32){
      const float* ks = QKV + qb + (size_t)((p+2)*32 + sm)*768 + 256 + sch*16;
      #pragma unroll
      for (int i = 0; i < 4; i++) k4[i] = *(const float4*)(ks + i*4);
    }
    {
      float ev[8], hv[8];
      *(float4*)&ev[0] = e4[p&1][0];
      *(float4*)&ev[4] = e4[p&1][1];
      if (p+2 < 32){
        e4[p&1][0] = *(const float4*)&E[erow + (size_t)(p+2)*256];
        e4[p&1][1] = *(const float4*)&E[erow + (size_t)(p+2)*256 + 4];
      }
      #pragma unroll
      for (int hh = 0; hh < 8; hh++){
        float s = sct[hh*528 + cl*33 + cu];
        float x = fminf(fmaxf(s, -5.f), 5.f) + ev[hh];
        hv[hh] = x;
        esum[hh] += __expf(x);
      }
      *(float4*)&out[OFF_H + erow + (size_t)p*256]     = *(float4*)&hv[0];
      *(float4*)&out[OFF_H + erow + (size_t)p*256 + 4] = *(float4*)&hv[4];
    }
    LBAR();
  }

  // ---- expsum reduce over cu (threads sharing l) ----
  float rcp8[8];
  #pragma unroll
  for (int hh = 0; hh < 8; hh++){
    float v = esum[hh];
    v += __shfl_xor(v, 1); v += __shfl_xor(v, 2); v += __shfl_xor(v, 4);
    v += __shfl_xor(v, 8); v += __shfl_xor(v, 16);
    rcp8[hh] = 1.f / v;
  }

  // ================= PHASE 2 =================
  float dsum[8] = {0.f,0.f,0.f,0.f,0.f,0.f,0.f,0.f};
  f32x4 vc0 = {0.f,0.f,0.f,0.f}, vc1 = {0.f,0.f,0.f,0.f};
  float4 v4[4], g4[2], h4[2];
  {
    const float* vs = QKV + qb + (size_t)sm*768 + 512 + sch*16;
    #pragma unroll
    for (int i = 0; i < 4; i++) v4[i] = *(const float4*)(vs + i*4);
    g4[0] = *(const float4*)&G[erow];
    g4[1] = *(const float4*)&G[erow + 4];
    h4[0] = *(const float4*)&out[OFF_H + erow];
    h4[1] = *(const float4*)&out[OFF_H + erow + 4];
  }
  __syncthreads();

  #pragma unroll 2
  for (int p = 0; p < 32; p++){
    // A: V(p)->vlds; elementwise A(p)->alds+global; issue p+1 loads
    {
      const float* vf_ = (const float*)v4;
      #pragma unroll
      for (int j = 0; j < 16; j++){
        int d = 2*sch + (j>>3), hh = j&7;
        vl16[hh*1280 + d*40 + sm] = (__fp16)vf_[j];
      }
      if (p+1 < 32){
        const float* vs = QKV + qb + (size_t)((p+1)*32 + sm)*768 + 512 + sch*16;
        #pragma unroll
        for (int i = 0; i < 4; i++) v4[i] = *(const float4*)(vs + i*4);
      }
      float gv[8], hvv[8], av[8];
      *(float4*)&gv[0]  = g4[0]; *(float4*)&gv[4]  = g4[1];
      *(float4*)&hvv[0] = h4[0]; *(float4*)&hvv[4] = h4[1];
      if (p+1 < 32){
        g4[0] = *(const float4*)&G[erow + (size_t)(p+1)*256];
        g4[1] = *(const float4*)&G[erow + (size_t)(p+1)*256 + 4];
        h4[0] = *(const float4*)&out[OFF_H + erow + (size_t)(p+1)*256];
        h4[1] = *(const float4*)&out[OFF_H + erow + (size_t)(p+1)*256 + 4];
      }
      #pragma unroll
      for (int hh = 0; hh < 8; hh++){
        float sig = 1.f / (1.f + __expf(-gv[hh]));
        float A = __expf(hvv[hh]) * rcp8[hh] * sig;
        dsum[hh] += sig;
        av[hh] = A;
        al16[hh*640 + cl*40 + cu] = (__fp16)A;
      }
      *(float4*)&out[OFF_A + erow + (size_t)p*256]     = *(float4*)&av[0];
      *(float4*)&out[OFF_A + erow + (size_t)p*256 + 4] = *(float4*)&av[4];
    }
    LBAR();
    // B: PV mfma (A rows l, k=m32; V cols d)
    {
      f16x8 af  = *(const f16x8*)&al16[wv*640 + c*40 + 8*g];
      f16x8 vf0 = *(const f16x8*)&vl16[wv*1280 + c*40 + 8*g];
      f16x8 vf1 = *(const f16x8*)&vl16[wv*1280 + (c+16)*40 + 8*g];
      vc0 = __builtin_amdgcn_mfma_f32_16x16x32_f16(af, vf0, vc0, 0, 0, 0);
      vc1 = __builtin_amdgcn_mfma_f32_16x16x32_f16(af, vf1, vc1, 0, 0, 0);
    }
    LBAR();
  }

  // ---- degrees reduce; scalers to LDS ----
  #pragma unroll
  for (int hh = 0; hh < 8; hh++){
    float v = dsum[hh];
    v += __shfl_xor(v, 1); v += __shfl_xor(v, 2); v += __shfl_xor(v, 4);
    v += __shfl_xor(v, 8); v += __shfl_xor(v, 16);
    dsum[hh] = v;
  }
  if (cu == 0){
    #pragma unroll
    for (int hh = 0; hh < 8; hh++) fin[cl*9 + hh] = log1pf(dsum[hh]);
  }
  __syncthreads();

  // ---- V_att store (mfma domain) ----
  #pragma unroll
  for (int r = 0; r < 4; r++){
    float scl = fin[(4*g+r)*9 + wv];
    const int ob = (b*1024 + l0 + 4*g + r)*256 + wv;
    out[ob + c*8]      = vc0[r] * scl;
    out[ob + (c+16)*8] = vc1[r] * scl;
  }
}

extern "C" void kernel_launch(void* const* d_in, const int* in_sizes, int n_in,
                              void* d_out, int out_size, void* d_ws, size_t ws_size,
                              hipStream_t stream) {
  const float* QKV = (const float*)d_in[0];
  const float* E   = (const float*)d_in[1];
  const float* G   = (const float*)d_in[2];
  float* out = (float*)d_out;
  egt_mfma2<<<dim3(256), 512, 0, stream>>>(QKV, E, G, out);
}